// Round 2
// baseline (5615.531 us; speedup 1.0000x reference)
//
#include <hip/hip_runtime.h>

// ---------------- problem constants ----------------
constexpr int Tn  = 256;     // timesteps
constexpr int INn = 10;      // input features
constexpr int Hn  = 20;      // hidden
constexpr int G4  = 80;      // 4*H
constexpr int Bn  = 8192;    // batch

constexpr int NB  = 256;     // cooperative grid blocks
constexpr int NT  = 256;     // threads per block
constexpr int NW  = NT / 64; // waves per block = 4
constexpr int BPB = Bn / NB; // batch rows per block = 32
constexpr int PREP = 81;     // padded s_pre leading dim (kills 2-way conflicts)

// ---------------- ws layout ----------------
// ring: 2 lines x NB slots of u64 {epoch<<32 | f32bits}; relaxed atomics only.
constexpr int WS_RING64 = 0;                     // u64 idx, 512 u64 = 4 KB
constexpr int WS_XMAX   = 1024;                  // u32 idx
constexpr int WS_SX     = 1025;                  // f32 x-scale
constexpr int WS_WIH    = 1088;                  // 800  quantized w_ih
constexpr int WS_WHH    = WS_WIH + G4 * INn;     // 1600 quantized w_hh
constexpr int WS_W1     = WS_WHH + G4 * Hn;      // 1280
constexpr int WS_W2     = WS_W1 + 64 * Hn;       // 2048
constexpr int WS_W3     = WS_W2 + 32 * 64;       // 160
constexpr int WS_END    = WS_W3 + 5 * 32;        // ~26 KB total

constexpr float SIGS = (float)(1.0 / 63.0);
constexpr float TANS = (float)(1.0 / 31.0);

__device__ __forceinline__ float wave_bmax64(float v) {
#pragma unroll
  for (int off = 32; off; off >>= 1) v = fmaxf(v, __shfl_xor(v, off, 64));
  return v;  // result in ALL lanes
}

// quant matching the reference op-for-op: clip, round(half-even), *scale
__device__ __forceinline__ float quantq(float v, float s, float lo, float hi) {
  return __fmul_rn(rintf(fminf(fmaxf(v / s, lo), hi)), s);
}
__device__ __forceinline__ float sigm(float v) {
  return 1.0f / (1.0f + expf(-v));
}

// Grid-wide max, epoch-tagged 2-deep ring, RELAXED agent atomics only.
// One __syncthreads; every wave polls all NB slots (4 per lane) and
// butterfly-reduces, so the result lands in every lane with no broadcast.
__device__ __forceinline__ float grid_max(float v, int inst,
                                          unsigned long long* ring,
                                          float* s_red) {
  const int tid = threadIdx.x;
  const int lane = tid & 63;
  v = wave_bmax64(v);
  if (lane == 0) s_red[tid >> 6] = v;
  __syncthreads();  // also orders this phase's LDS writes before next reads
  if (tid == 0) {
    float bm = fmaxf(fmaxf(s_red[0], s_red[1]), fmaxf(s_red[2], s_red[3]));
    unsigned long long w =
        ((unsigned long long)(unsigned)inst << 32) | __float_as_uint(bm);
    __hip_atomic_store(&ring[(inst & 1) * NB + blockIdx.x], w,
                       __ATOMIC_RELAXED, __HIP_MEMORY_SCOPE_AGENT);
  }
  const int i0 = (inst & 1) * NB + lane * 4;
  const unsigned ep = (unsigned)inst;
  unsigned long long w0, w1, w2, w3;
  do {
    w0 = __hip_atomic_load(&ring[i0 + 0], __ATOMIC_RELAXED, __HIP_MEMORY_SCOPE_AGENT);
    w1 = __hip_atomic_load(&ring[i0 + 1], __ATOMIC_RELAXED, __HIP_MEMORY_SCOPE_AGENT);
    w2 = __hip_atomic_load(&ring[i0 + 2], __ATOMIC_RELAXED, __HIP_MEMORY_SCOPE_AGENT);
    w3 = __hip_atomic_load(&ring[i0 + 3], __ATOMIC_RELAXED, __HIP_MEMORY_SCOPE_AGENT);
  } while ((unsigned)(w0 >> 32) != ep || (unsigned)(w1 >> 32) != ep ||
           (unsigned)(w2 >> 32) != ep || (unsigned)(w3 >> 32) != ep);
  float m = fmaxf(fmaxf(__uint_as_float((unsigned)w0), __uint_as_float((unsigned)w1)),
                  fmaxf(__uint_as_float((unsigned)w2), __uint_as_float((unsigned)w3)));
  return wave_bmax64(m);
}

// ---------------- setup kernels ----------------
__global__ void k_init(unsigned long long* ring, unsigned* wsu) {
  int i = threadIdx.x;  // 512 threads
  if (i < 2 * NB) ring[WS_RING64 + i] = 0xFFFFFFFF00000000ull;
  if (i == 0) wsu[WS_XMAX] = 0u;
}

__global__ void k_xmax(const float4* __restrict__ x4, unsigned* wsu) {
  float m = 0.f;
  int idx = blockIdx.x * blockDim.x + threadIdx.x;
  int stride = gridDim.x * blockDim.x;
  for (int i = idx; i < (Bn * Tn * INn) / 4; i += stride) {
    float4 v = x4[i];
    m = fmaxf(m, fmaxf(fmaxf(fabsf(v.x), fabsf(v.y)),
                       fmaxf(fabsf(v.z), fabsf(v.w))));
  }
  m = wave_bmax64(m);
  __shared__ float sred[4];
  if ((threadIdx.x & 63) == 0) sred[threadIdx.x >> 6] = m;
  __syncthreads();
  if (threadIdx.x == 0) {
    m = fmaxf(fmaxf(sred[0], sred[1]), fmaxf(sred[2], sred[3]));
    atomicMax(&wsu[WS_XMAX], __float_as_uint(m));  // non-neg f32: bit-monotone
  }
}

__device__ void quant_tensor(const float* __restrict__ src, int n, float* dst,
                             float* sred, float* sb, int nt) {
  const int tid = threadIdx.x;
  float m = 0.f;
  for (int i = tid; i < n; i += nt) m = fmaxf(m, fabsf(src[i]));
  m = wave_bmax64(m);
  __syncthreads();
  if ((tid & 63) == 0) sred[tid >> 6] = m;
  __syncthreads();
  if (tid == 0) {
    float bm = sred[0];
    for (int w = 1; w < nt / 64; ++w) bm = fmaxf(bm, sred[w]);
    *sb = __fadd_rn(bm / 127.0f, 1e-8f);
  }
  __syncthreads();
  float s = *sb;
  for (int i = tid; i < n; i += nt) {
    float q = rintf(fminf(fmaxf(src[i] / s, -128.f), 127.f));
    dst[i] = __fmul_rn(q, s);
  }
}

__global__ __launch_bounds__(1024) void k_wq(const float* wih, const float* whh,
                                             const float* w1, const float* w2,
                                             const float* w3, unsigned* wsu) {
  float* wsf = (float*)wsu;
  __shared__ float sred[16];
  __shared__ float sb;
  if (threadIdx.x == 0)
    wsf[WS_SX] = __fadd_rn(__uint_as_float(wsu[WS_XMAX]) / 127.0f, 1e-8f);
  quant_tensor(wih, G4 * INn, wsf + WS_WIH, sred, &sb, 1024);
  quant_tensor(whh, G4 * Hn,  wsf + WS_WHH, sred, &sb, 1024);
  quant_tensor(w1,  64 * Hn,  wsf + WS_W1,  sred, &sb, 1024);
  quant_tensor(w2,  32 * 64,  wsf + WS_W2,  sred, &sb, 1024);
  quant_tensor(w3,  5 * 32,   wsf + WS_W3,  sred, &sb, 1024);
}

// ---------------- main cooperative LSTM kernel ----------------
__global__ __launch_bounds__(NT, 1) void k_lstm(
    const float* __restrict__ x,
    const float* __restrict__ bih, const float* __restrict__ bhh,
    const float* __restrict__ b1, const float* __restrict__ b2,
    const float* __restrict__ b3,
    float* __restrict__ out, unsigned* __restrict__ wsu) {
  const float* wsf = (const float*)wsu;
  unsigned long long* ring = (unsigned long long*)wsu;

  __shared__ float s_wih[G4][INn];
  __shared__ float s_whh[G4][Hn];
  __shared__ float s_bih[G4], s_bhh[G4];
  __shared__ float s_h[BPB][Hn];       // persistent hidden state
  __shared__ float s_c[BPB][Hn];       // persistent cell state
  __shared__ float s_pre[BPB][PREP];   // pre-gates (padded); reused as l1
  __shared__ float s_xs[BPB][INn];     // quantized x slice for current step
  __shared__ float s_l2[BPB][32];
  __shared__ float s_red[NW];

  const int tid = threadIdx.x;
  const int b0 = blockIdx.x * BPB;

  for (int i = tid; i < G4 * INn; i += NT) (&s_wih[0][0])[i] = wsf[WS_WIH + i];
  for (int i = tid; i < G4 * Hn; i += NT) (&s_whh[0][0])[i] = wsf[WS_WHH + i];
  if (tid < G4) { s_bih[tid] = bih[tid]; s_bhh[tid] = bhh[tid]; }
  for (int i = tid; i < BPB * Hn; i += NT) {
    (&s_h[0][0])[i] = 0.f;
    (&s_c[0][0])[i] = 0.f;
  }
  const float sx = wsf[WS_SX];

  const int bl = tid >> 3;        // batch row (0..31) for matmul
  const int g0 = (tid & 7) * 10;  // first of 10 gate columns

  // x prefetch mapping: e0 = tid (always < 320), e1 = 256+tid (tid<64)
  const int bi0 = tid / INn, ii0 = tid - bi0 * INn;
  const int e1 = NT + tid;
  const int bi1 = e1 / INn, ii1 = e1 - bi1 * INn;
  const bool has1 = (e1 < BPB * INn);

  // stage + quantize x(t=0)
  {
    float v = x[((b0 + bi0) * Tn + 0) * INn + ii0];
    s_xs[bi0][ii0] = __fmul_rn(rintf(fminf(fmaxf(v / sx, -128.f), 127.f)), sx);
    if (has1) {
      float v1 = x[((b0 + bi1) * Tn + 0) * INn + ii1];
      s_xs[bi1][ii1] = __fmul_rn(rintf(fminf(fmaxf(v1 / sx, -128.f), 127.f)), sx);
    }
  }

  int inst = 0;
  __syncthreads();

  for (int t = 0; t < Tn; ++t) {
    // ---- pre-gates: xq@wih^T + b_ih + b_hh + h@whh^T ----
    float hreg[Hn], xreg[INn];
#pragma unroll
    for (int k = 0; k < Hn; k++) hreg[k] = s_h[bl][k];
#pragma unroll
    for (int i = 0; i < INn; i++) xreg[i] = s_xs[bl][i];
    float lm = 0.f;
#pragma unroll
    for (int gg = 0; gg < 10; ++gg) {
      int g = g0 + gg;
      float acc = 0.f;
#pragma unroll
      for (int i = 0; i < INn; i++) acc = fmaf(xreg[i], s_wih[g][i], acc);
      acc = __fadd_rn(acc, s_bih[g]);
      acc = __fadd_rn(acc, s_bhh[g]);
      float hd = 0.f;
#pragma unroll
      for (int k = 0; k < Hn; k++) hd = fmaf(hreg[k], s_whh[g][k], hd);
      float pre = __fadd_rn(acc, hd);
      s_pre[bl][g] = pre;
      lm = fmaxf(lm, fabsf(pre));
    }
    float s1 = __fadd_rn(grid_max(lm, inst++, ring, s_red) / 31.0f, 1e-8f);

    // ---- gate quant + nonlinearities + cell pre-activation ----
    float cpre[3], og[3], hpre[3];
    float lm2 = 0.f;
#pragma unroll
    for (int k = 0; k < 3; k++) {
      int e = tid + k * NT;
      if (e < BPB * Hn) {
        int cb = e / Hn, j = e - cb * Hn;
        float gi = quantq(s_pre[cb][j],      s1, -32.f, 31.f);
        float gf = quantq(s_pre[cb][20 + j], s1, -32.f, 31.f);
        float gg = quantq(s_pre[cb][40 + j], s1, -32.f, 31.f);
        float go = quantq(s_pre[cb][60 + j], s1, -32.f, 31.f);
        float iv = quantq(sigm(gi), SIGS, 0.f, 63.f);
        float fv = quantq(sigm(gf), SIGS, 0.f, 63.f);
        float gv = quantq(tanhf(gg), TANS, -32.f, 31.f);
        og[k]    = quantq(sigm(go), SIGS, 0.f, 63.f);
        float cp = __fadd_rn(__fmul_rn(fv, s_c[cb][j]), __fmul_rn(iv, gv));
        cpre[k] = cp;
        lm2 = fmaxf(lm2, fabsf(cp));
      }
    }

    // issue x(t+1) prefetch; completion overlaps the s2 poll window
    float xr0 = 0.f, xr1 = 0.f;
    if (t + 1 < Tn) {
      xr0 = x[((b0 + bi0) * Tn + (t + 1)) * INn + ii0];
      if (has1) xr1 = x[((b0 + bi1) * Tn + (t + 1)) * INn + ii1];
    }

    float s2 = __fadd_rn(grid_max(lm2, inst++, ring, s_red) / 31.0f, 1e-8f);

    float lm3 = 0.f;
#pragma unroll
    for (int k = 0; k < 3; k++) {
      int e = tid + k * NT;
      if (e < BPB * Hn) {
        int cb = e / Hn, j = e - cb * Hn;
        float cn = quantq(cpre[k], s2, -32.f, 31.f);
        s_c[cb][j] = cn;
        float tq = quantq(tanhf(cn), TANS, -32.f, 31.f);
        float hp = __fmul_rn(og[k], tq);
        hpre[k] = hp;
        lm3 = fmaxf(lm3, fabsf(hp));
      }
    }
    float s3 = __fadd_rn(grid_max(lm3, inst++, ring, s_red) / 127.0f, 1e-8f);

#pragma unroll
    for (int k = 0; k < 3; k++) {
      int e = tid + k * NT;
      if (e < BPB * Hn) {
        int cb = e / Hn, j = e - cb * Hn;
        s_h[cb][j] = quantq(hpre[k], s3, -128.f, 127.f);
      }
    }
    // write prefetched x(t+1) (s_xs reads for step t all completed before
    // the s1 grid_max barrier)
    if (t + 1 < Tn) {
      s_xs[bi0][ii0] = __fmul_rn(rintf(fminf(fmaxf(xr0 / sx, -128.f), 127.f)), sx);
      if (has1)
        s_xs[bi1][ii1] = __fmul_rn(rintf(fminf(fmaxf(xr1 / sx, -128.f), 127.f)), sx);
    }
    __syncthreads();  // order s_h / s_xs writes before next matmul reads
  }

  // ---------------- MLP head ----------------
  // out0 = qrelu(hT, 6), in place in s_h
  {
    float r[3];
    float lm = 0.f;
#pragma unroll
    for (int k = 0; k < 3; k++) {
      int e = tid + k * NT;
      if (e < BPB * Hn) {
        r[k] = fmaxf((&s_h[0][0])[e], 0.f);
        lm = fmaxf(lm, r[k]);
      }
    }
    float s = __fadd_rn(grid_max(lm, inst++, ring, s_red) / 63.0f, 1e-8f);
#pragma unroll
    for (int k = 0; k < 3; k++) {
      int e = tid + k * NT;
      if (e < BPB * Hn)
        (&s_h[0][0])[e] = __fmul_rn(rintf(fminf(fmaxf(r[k] / s, 0.f), 63.f)), s);
    }
  }
  __syncthreads();

  // l1 = qrelu(out0 @ w1^T + b1, 6) -> s_l1 (aliases s_pre, 2048 <= 32*81)
  float* s_l1 = &s_pre[0][0];
  {
    float a[8];
    float lm = 0.f;
#pragma unroll
    for (int k = 0; k < 8; k++) {
      int o = tid + k * NT;
      int cb = o >> 6, j = o & 63;
      float acc = 0.f;
#pragma unroll
      for (int kk = 0; kk < Hn; kk++)
        acc = fmaf(s_h[cb][kk], wsf[WS_W1 + j * Hn + kk], acc);
      acc = __fadd_rn(acc, b1[j]);
      acc = fmaxf(acc, 0.f);
      a[k] = acc;
      lm = fmaxf(lm, acc);
    }
    float s = __fadd_rn(grid_max(lm, inst++, ring, s_red) / 63.0f, 1e-8f);
#pragma unroll
    for (int k = 0; k < 8; k++) {
      int o = tid + k * NT;
      s_l1[o] = __fmul_rn(rintf(fminf(fmaxf(a[k] / s, 0.f), 63.f)), s);
    }
  }
  __syncthreads();

  // l2 = qrelu(l1 @ w2^T + b2, 6) -> s_l2
  {
    float a[4];
    float lm = 0.f;
#pragma unroll
    for (int k = 0; k < 4; k++) {
      int o = tid + k * NT;
      int cb = o >> 5, j = o & 31;
      float acc = 0.f;
#pragma unroll
      for (int kk = 0; kk < 64; kk++)
        acc = fmaf(s_l1[cb * 64 + kk], wsf[WS_W2 + j * 64 + kk], acc);
      acc = __fadd_rn(acc, b2[j]);
      acc = fmaxf(acc, 0.f);
      a[k] = acc;
      lm = fmaxf(lm, acc);
    }
    float s = __fadd_rn(grid_max(lm, inst++, ring, s_red) / 63.0f, 1e-8f);
#pragma unroll
    for (int k = 0; k < 4; k++) {
      int o = tid + k * NT;
      int cb = o >> 5, j = o & 31;
      s_l2[cb][j] = __fmul_rn(rintf(fminf(fmaxf(a[k] / s, 0.f), 63.f)), s);
    }
  }
  __syncthreads();

  // out = l2 @ w3^T + b3
  if (tid < BPB * 5) {
    int cb = tid / 5, j = tid - cb * 5;
    float acc = 0.f;
#pragma unroll
    for (int kk = 0; kk < 32; kk++)
      acc = fmaf(s_l2[cb][kk], wsf[WS_W3 + j * 32 + kk], acc);
    acc = __fadd_rn(acc, b3[j]);
    out[(b0 + cb) * 5 + j] = acc;
  }
}

extern "C" void kernel_launch(void* const* d_in, const int* in_sizes, int n_in,
                              void* d_out, int out_size, void* d_ws,
                              size_t ws_size, hipStream_t stream) {
  const float* x   = (const float*)d_in[0];
  const float* wih = (const float*)d_in[1];
  const float* whh = (const float*)d_in[2];
  const float* bih = (const float*)d_in[3];
  const float* bhh = (const float*)d_in[4];
  const float* w1  = (const float*)d_in[5];
  const float* b1  = (const float*)d_in[6];
  const float* w2  = (const float*)d_in[7];
  const float* b2  = (const float*)d_in[8];
  const float* w3  = (const float*)d_in[9];
  const float* b3  = (const float*)d_in[10];
  float* out = (float*)d_out;
  unsigned* wsu = (unsigned*)d_ws;
  unsigned long long* ring = (unsigned long long*)d_ws;

  k_init<<<dim3(1), dim3(512), 0, stream>>>(ring, wsu);
  k_xmax<<<dim3(512), dim3(256), 0, stream>>>((const float4*)x, wsu);
  k_wq<<<dim3(1), dim3(1024), 0, stream>>>(wih, whh, w1, w2, w3, wsu);

  void* args[] = {(void*)&x,  (void*)&bih, (void*)&bhh, (void*)&b1,
                  (void*)&b2, (void*)&b3,  (void*)&out, (void*)&wsu};
  hipLaunchCooperativeKernel(k_lstm, dim3(NB), dim3(NT), args, 0, stream);
}

// Round 3
// 2739.544 us; speedup vs baseline: 2.0498x; 2.0498x over previous
//
#include <hip/hip_runtime.h>

// ---------------- problem constants ----------------
constexpr int Tn  = 256;     // timesteps
constexpr int INn = 10;      // input features
constexpr int Hn  = 20;      // hidden
constexpr int G4  = 80;      // 4*H
constexpr int Bn  = 8192;    // batch

constexpr int NB  = 256;     // cooperative grid blocks
constexpr int NT  = 256;     // threads per block
constexpr int NW  = NT / 64; // waves per block = 4
constexpr int BPB = Bn / NB; // batch rows per block = 32
constexpr int PREP = 81;     // padded s_pre leading dim

// ---------------- ws layout ----------------
// ring (u64): [2][NB] partial slots + [2] broadcast words; relaxed atomics.
constexpr int RING_SLOTS = 0;        // u64 idx: [line][block]
constexpr int RING_BCAST = 2 * NB;   // u64 idx: [line]
constexpr int RING_U64   = 2 * NB + 2;  // 514

constexpr int WS_XMAX   = 1040;                  // u32 idx (past ring)
constexpr int WS_SX     = 1041;                  // f32 x-scale
constexpr int WS_WIH    = 1088;                  // 800  quantized w_ih
constexpr int WS_WHH    = WS_WIH + G4 * INn;     // 1600 quantized w_hh
constexpr int WS_W1     = WS_WHH + G4 * Hn;      // 1280
constexpr int WS_W2     = WS_W1 + 64 * Hn;       // 2048
constexpr int WS_W3     = WS_W2 + 32 * 64;       // 160
constexpr int WS_END    = WS_W3 + 5 * 32;        // ~26 KB total

constexpr float SIGS = (float)(1.0 / 63.0);
constexpr float TANS = (float)(1.0 / 31.0);

__device__ __forceinline__ float wave_bmax64(float v) {
#pragma unroll
  for (int off = 32; off; off >>= 1) v = fmaxf(v, __shfl_xor(v, off, 64));
  return v;  // result in ALL lanes
}

// quant matching the reference op-for-op: clip, round(half-even), *scale
__device__ __forceinline__ float quantq(float v, float s, float lo, float hi) {
  return __fmul_rn(rintf(fminf(fmaxf(v / s, lo), hi)), s);
}
__device__ __forceinline__ float sigm(float v) {
  return 1.0f / (1.0f + expf(-v));
}

__device__ __forceinline__ unsigned long long ring_ld(unsigned long long* p) {
  return __hip_atomic_load(p, __ATOMIC_RELAXED, __HIP_MEMORY_SCOPE_AGENT);
}
__device__ __forceinline__ void ring_st(unsigned long long* p,
                                        unsigned long long v) {
  __hip_atomic_store(p, v, __ATOMIC_RELAXED, __HIP_MEMORY_SCOPE_AGENT);
}

// Grid-wide max, two-hop minimal-traffic tree:
//   all blocks: tid0 stores epoch-tagged partial to its private slot
//   block 0 / wave 0: polls 256 slots (4/lane), reduces, publishes 1 bcast word
//   other blocks: single lane polls the bcast word; LDS broadcast
// 2-deep ring (inst&1) is WAR-safe: a block reaches inst only after block 0
// published inst-1, which required every partial of inst-1 (different line).
__device__ __forceinline__ float grid_max(float v, int inst,
                                          unsigned long long* ring,
                                          float* s_red, float* s_bc) {
  const int tid = threadIdx.x;
  v = wave_bmax64(v);
  if ((tid & 63) == 0) s_red[tid >> 6] = v;
  __syncthreads();  // also orders this phase's LDS writes before next reads
  const unsigned ep = (unsigned)inst;
  const int line = inst & 1;
  if (blockIdx.x == 0) {
    if (tid < 64) {
      if (tid == 0) {
        float bm = fmaxf(fmaxf(s_red[0], s_red[1]), fmaxf(s_red[2], s_red[3]));
        ring_st(&ring[RING_SLOTS + line * NB + 0],
                ((unsigned long long)ep << 32) | __float_as_uint(bm));
      }
      const int i0 = RING_SLOTS + line * NB + tid * 4;
      unsigned long long w0, w1, w2, w3;
      do {
        w0 = ring_ld(&ring[i0 + 0]);
        w1 = ring_ld(&ring[i0 + 1]);
        w2 = ring_ld(&ring[i0 + 2]);
        w3 = ring_ld(&ring[i0 + 3]);
      } while ((unsigned)(w0 >> 32) != ep || (unsigned)(w1 >> 32) != ep ||
               (unsigned)(w2 >> 32) != ep || (unsigned)(w3 >> 32) != ep);
      float m = fmaxf(
          fmaxf(__uint_as_float((unsigned)w0), __uint_as_float((unsigned)w1)),
          fmaxf(__uint_as_float((unsigned)w2), __uint_as_float((unsigned)w3)));
      m = wave_bmax64(m);
      if (tid == 0) {
        ring_st(&ring[RING_BCAST + line],
                ((unsigned long long)ep << 32) | __float_as_uint(m));
        *s_bc = m;
      }
    }
  } else {
    if (tid == 0) {
      float bm = fmaxf(fmaxf(s_red[0], s_red[1]), fmaxf(s_red[2], s_red[3]));
      ring_st(&ring[RING_SLOTS + line * NB + blockIdx.x],
              ((unsigned long long)ep << 32) | __float_as_uint(bm));
      unsigned long long w;
      do {
        w = ring_ld(&ring[RING_BCAST + line]);
      } while ((unsigned)(w >> 32) != ep);
      *s_bc = __uint_as_float((unsigned)w);
    }
  }
  __syncthreads();
  return *s_bc;
}

// ---------------- setup kernels ----------------
__global__ void k_init(unsigned long long* ring, unsigned* wsu) {
  int i = threadIdx.x;  // 1024 threads
  if (i < RING_U64) ring[i] = 0xFFFFFFFF00000000ull;
  if (i == 0) wsu[WS_XMAX] = 0u;
}

__global__ void k_xmax(const float4* __restrict__ x4, unsigned* wsu) {
  float m = 0.f;
  int idx = blockIdx.x * blockDim.x + threadIdx.x;
  int stride = gridDim.x * blockDim.x;
  for (int i = idx; i < (Bn * Tn * INn) / 4; i += stride) {
    float4 v = x4[i];
    m = fmaxf(m, fmaxf(fmaxf(fabsf(v.x), fabsf(v.y)),
                       fmaxf(fabsf(v.z), fabsf(v.w))));
  }
  m = wave_bmax64(m);
  __shared__ float sred[4];
  if ((threadIdx.x & 63) == 0) sred[threadIdx.x >> 6] = m;
  __syncthreads();
  if (threadIdx.x == 0) {
    m = fmaxf(fmaxf(sred[0], sred[1]), fmaxf(sred[2], sred[3]));
    atomicMax(&wsu[WS_XMAX], __float_as_uint(m));  // non-neg f32: bit-monotone
  }
}

__device__ void quant_tensor(const float* __restrict__ src, int n, float* dst,
                             float* sred, float* sb, int nt) {
  const int tid = threadIdx.x;
  float m = 0.f;
  for (int i = tid; i < n; i += nt) m = fmaxf(m, fabsf(src[i]));
  m = wave_bmax64(m);
  __syncthreads();
  if ((tid & 63) == 0) sred[tid >> 6] = m;
  __syncthreads();
  if (tid == 0) {
    float bm = sred[0];
    for (int w = 1; w < nt / 64; ++w) bm = fmaxf(bm, sred[w]);
    *sb = __fadd_rn(bm / 127.0f, 1e-8f);
  }
  __syncthreads();
  float s = *sb;
  for (int i = tid; i < n; i += nt) {
    float q = rintf(fminf(fmaxf(src[i] / s, -128.f), 127.f));
    dst[i] = __fmul_rn(q, s);
  }
}

__global__ __launch_bounds__(1024) void k_wq(const float* wih, const float* whh,
                                             const float* w1, const float* w2,
                                             const float* w3, unsigned* wsu) {
  float* wsf = (float*)wsu;
  __shared__ float sred[16];
  __shared__ float sb;
  if (threadIdx.x == 0)
    wsf[WS_SX] = __fadd_rn(__uint_as_float(wsu[WS_XMAX]) / 127.0f, 1e-8f);
  quant_tensor(wih, G4 * INn, wsf + WS_WIH, sred, &sb, 1024);
  quant_tensor(whh, G4 * Hn,  wsf + WS_WHH, sred, &sb, 1024);
  quant_tensor(w1,  64 * Hn,  wsf + WS_W1,  sred, &sb, 1024);
  quant_tensor(w2,  32 * 64,  wsf + WS_W2,  sred, &sb, 1024);
  quant_tensor(w3,  5 * 32,   wsf + WS_W3,  sred, &sb, 1024);
}

// ---------------- main cooperative LSTM kernel ----------------
__global__ __launch_bounds__(NT, 1) void k_lstm(
    const float* __restrict__ x,
    const float* __restrict__ bih, const float* __restrict__ bhh,
    const float* __restrict__ b1, const float* __restrict__ b2,
    const float* __restrict__ b3,
    float* __restrict__ out, unsigned* __restrict__ wsu) {
  const float* wsf = (const float*)wsu;
  unsigned long long* ring = (unsigned long long*)wsu;

  __shared__ float s_wih[G4][INn];
  __shared__ float s_whh[G4][Hn];
  __shared__ float s_bih[G4], s_bhh[G4];
  __shared__ float s_h[BPB][Hn];       // persistent hidden state
  __shared__ float s_c[BPB][Hn];       // persistent cell state
  __shared__ float s_pre[BPB][PREP];   // pre-gates (padded); reused as l1
  __shared__ float s_xs[BPB][INn];     // quantized x slice for current step
  __shared__ float s_l2[BPB][32];
  __shared__ float s_red[NW];
  __shared__ float s_bc;

  const int tid = threadIdx.x;
  const int b0 = blockIdx.x * BPB;

  for (int i = tid; i < G4 * INn; i += NT) (&s_wih[0][0])[i] = wsf[WS_WIH + i];
  for (int i = tid; i < G4 * Hn; i += NT) (&s_whh[0][0])[i] = wsf[WS_WHH + i];
  if (tid < G4) { s_bih[tid] = bih[tid]; s_bhh[tid] = bhh[tid]; }
  for (int i = tid; i < BPB * Hn; i += NT) {
    (&s_h[0][0])[i] = 0.f;
    (&s_c[0][0])[i] = 0.f;
  }
  const float sx = wsf[WS_SX];

  const int bl = tid >> 3;        // batch row (0..31) for matmul
  const int g0 = (tid & 7) * 10;  // first of 10 gate columns

  // x prefetch mapping: e0 = tid (always < 320), e1 = 256+tid (tid<64)
  const int bi0 = tid / INn, ii0 = tid - bi0 * INn;
  const int e1 = NT + tid;
  const int bi1 = e1 / INn, ii1 = e1 - bi1 * INn;
  const bool has1 = (e1 < BPB * INn);

  // stage + quantize x(t=0)
  {
    float v = x[((b0 + bi0) * Tn + 0) * INn + ii0];
    s_xs[bi0][ii0] = __fmul_rn(rintf(fminf(fmaxf(v / sx, -128.f), 127.f)), sx);
    if (has1) {
      float v1 = x[((b0 + bi1) * Tn + 0) * INn + ii1];
      s_xs[bi1][ii1] = __fmul_rn(rintf(fminf(fmaxf(v1 / sx, -128.f), 127.f)), sx);
    }
  }

  int inst = 0;
  __syncthreads();

  for (int t = 0; t < Tn; ++t) {
    // ---- pre-gates: xq@wih^T + b_ih + b_hh + h@whh^T ----
    float hreg[Hn], xreg[INn];
#pragma unroll
    for (int k = 0; k < Hn; k++) hreg[k] = s_h[bl][k];
#pragma unroll
    for (int i = 0; i < INn; i++) xreg[i] = s_xs[bl][i];
    float lm = 0.f;
#pragma unroll
    for (int gg = 0; gg < 10; ++gg) {
      int g = g0 + gg;
      float acc = 0.f;
#pragma unroll
      for (int i = 0; i < INn; i++) acc = fmaf(xreg[i], s_wih[g][i], acc);
      acc = __fadd_rn(acc, s_bih[g]);
      acc = __fadd_rn(acc, s_bhh[g]);
      float hd = 0.f;
#pragma unroll
      for (int k = 0; k < Hn; k++) hd = fmaf(hreg[k], s_whh[g][k], hd);
      float pre = __fadd_rn(acc, hd);
      s_pre[bl][g] = pre;
      lm = fmaxf(lm, fabsf(pre));
    }
    float s1 = __fadd_rn(grid_max(lm, inst++, ring, s_red, &s_bc) / 31.0f, 1e-8f);

    // ---- gate quant + nonlinearities + cell pre-activation ----
    float cpre[3], og[3], hpre[3];
    float lm2 = 0.f;
#pragma unroll
    for (int k = 0; k < 3; k++) {
      int e = tid + k * NT;
      if (e < BPB * Hn) {
        int cb = e / Hn, j = e - cb * Hn;
        float gi = quantq(s_pre[cb][j],      s1, -32.f, 31.f);
        float gf = quantq(s_pre[cb][20 + j], s1, -32.f, 31.f);
        float gg = quantq(s_pre[cb][40 + j], s1, -32.f, 31.f);
        float go = quantq(s_pre[cb][60 + j], s1, -32.f, 31.f);
        float iv = quantq(sigm(gi), SIGS, 0.f, 63.f);
        float fv = quantq(sigm(gf), SIGS, 0.f, 63.f);
        float gv = quantq(tanhf(gg), TANS, -32.f, 31.f);
        og[k]    = quantq(sigm(go), SIGS, 0.f, 63.f);
        float cp = __fadd_rn(__fmul_rn(fv, s_c[cb][j]), __fmul_rn(iv, gv));
        cpre[k] = cp;
        lm2 = fmaxf(lm2, fabsf(cp));
      }
    }

    // issue x(t+1) prefetch; completion overlaps the s2 poll window
    float xr0 = 0.f, xr1 = 0.f;
    if (t + 1 < Tn) {
      xr0 = x[((b0 + bi0) * Tn + (t + 1)) * INn + ii0];
      if (has1) xr1 = x[((b0 + bi1) * Tn + (t + 1)) * INn + ii1];
    }

    float s2 = __fadd_rn(grid_max(lm2, inst++, ring, s_red, &s_bc) / 31.0f, 1e-8f);

    float lm3 = 0.f;
#pragma unroll
    for (int k = 0; k < 3; k++) {
      int e = tid + k * NT;
      if (e < BPB * Hn) {
        int cb = e / Hn, j = e - cb * Hn;
        float cn = quantq(cpre[k], s2, -32.f, 31.f);
        s_c[cb][j] = cn;
        float tq = quantq(tanhf(cn), TANS, -32.f, 31.f);
        float hp = __fmul_rn(og[k], tq);
        hpre[k] = hp;
        lm3 = fmaxf(lm3, fabsf(hp));
      }
    }
    float s3 = __fadd_rn(grid_max(lm3, inst++, ring, s_red, &s_bc) / 127.0f, 1e-8f);

#pragma unroll
    for (int k = 0; k < 3; k++) {
      int e = tid + k * NT;
      if (e < BPB * Hn) {
        int cb = e / Hn, j = e - cb * Hn;
        s_h[cb][j] = quantq(hpre[k], s3, -128.f, 127.f);
      }
    }
    // write prefetched x(t+1) (s_xs reads for step t completed before the
    // s1 grid_max barrier)
    if (t + 1 < Tn) {
      s_xs[bi0][ii0] = __fmul_rn(rintf(fminf(fmaxf(xr0 / sx, -128.f), 127.f)), sx);
      if (has1)
        s_xs[bi1][ii1] = __fmul_rn(rintf(fminf(fmaxf(xr1 / sx, -128.f), 127.f)), sx);
    }
    __syncthreads();  // order s_h / s_xs writes before next matmul reads
  }

  // ---------------- MLP head ----------------
  // out0 = qrelu(hT, 6), in place in s_h
  {
    float r[3];
    float lm = 0.f;
#pragma unroll
    for (int k = 0; k < 3; k++) {
      int e = tid + k * NT;
      if (e < BPB * Hn) {
        r[k] = fmaxf((&s_h[0][0])[e], 0.f);
        lm = fmaxf(lm, r[k]);
      }
    }
    float s = __fadd_rn(grid_max(lm, inst++, ring, s_red, &s_bc) / 63.0f, 1e-8f);
#pragma unroll
    for (int k = 0; k < 3; k++) {
      int e = tid + k * NT;
      if (e < BPB * Hn)
        (&s_h[0][0])[e] = __fmul_rn(rintf(fminf(fmaxf(r[k] / s, 0.f), 63.f)), s);
    }
  }
  __syncthreads();

  // l1 = qrelu(out0 @ w1^T + b1, 6) -> s_l1 (aliases s_pre, 2048 <= 32*81)
  float* s_l1 = &s_pre[0][0];
  {
    float a[8];
    float lm = 0.f;
#pragma unroll
    for (int k = 0; k < 8; k++) {
      int o = tid + k * NT;
      int cb = o >> 6, j = o & 63;
      float acc = 0.f;
#pragma unroll
      for (int kk = 0; kk < Hn; kk++)
        acc = fmaf(s_h[cb][kk], wsf[WS_W1 + j * Hn + kk], acc);
      acc = __fadd_rn(acc, b1[j]);
      acc = fmaxf(acc, 0.f);
      a[k] = acc;
      lm = fmaxf(lm, acc);
    }
    float s = __fadd_rn(grid_max(lm, inst++, ring, s_red, &s_bc) / 63.0f, 1e-8f);
#pragma unroll
    for (int k = 0; k < 8; k++) {
      int o = tid + k * NT;
      s_l1[o] = __fmul_rn(rintf(fminf(fmaxf(a[k] / s, 0.f), 63.f)), s);
    }
  }
  __syncthreads();

  // l2 = qrelu(l1 @ w2^T + b2, 6) -> s_l2
  {
    float a[4];
    float lm = 0.f;
#pragma unroll
    for (int k = 0; k < 4; k++) {
      int o = tid + k * NT;
      int cb = o >> 5, j = o & 31;
      float acc = 0.f;
#pragma unroll
      for (int kk = 0; kk < 64; kk++)
        acc = fmaf(s_l1[cb * 64 + kk], wsf[WS_W2 + j * 64 + kk], acc);
      acc = __fadd_rn(acc, b2[j]);
      acc = fmaxf(acc, 0.f);
      a[k] = acc;
      lm = fmaxf(lm, acc);
    }
    float s = __fadd_rn(grid_max(lm, inst++, ring, s_red, &s_bc) / 63.0f, 1e-8f);
#pragma unroll
    for (int k = 0; k < 4; k++) {
      int o = tid + k * NT;
      int cb = o >> 5, j = o & 31;
      s_l2[cb][j] = __fmul_rn(rintf(fminf(fmaxf(a[k] / s, 0.f), 63.f)), s);
    }
  }
  __syncthreads();

  // out = l2 @ w3^T + b3
  if (tid < BPB * 5) {
    int cb = tid / 5, j = tid - cb * 5;
    float acc = 0.f;
#pragma unroll
    for (int kk = 0; kk < 32; kk++)
      acc = fmaf(s_l2[cb][kk], wsf[WS_W3 + j * 32 + kk], acc);
    acc = __fadd_rn(acc, b3[j]);
    out[(b0 + cb) * 5 + j] = acc;
  }
}

extern "C" void kernel_launch(void* const* d_in, const int* in_sizes, int n_in,
                              void* d_out, int out_size, void* d_ws,
                              size_t ws_size, hipStream_t stream) {
  const float* x   = (const float*)d_in[0];
  const float* wih = (const float*)d_in[1];
  const float* whh = (const float*)d_in[2];
  const float* bih = (const float*)d_in[3];
  const float* bhh = (const float*)d_in[4];
  const float* w1  = (const float*)d_in[5];
  const float* b1  = (const float*)d_in[6];
  const float* w2  = (const float*)d_in[7];
  const float* b2  = (const float*)d_in[8];
  const float* w3  = (const float*)d_in[9];
  const float* b3  = (const float*)d_in[10];
  float* out = (float*)d_out;
  unsigned* wsu = (unsigned*)d_ws;
  unsigned long long* ring = (unsigned long long*)d_ws;

  k_init<<<dim3(1), dim3(1024), 0, stream>>>(ring, wsu);
  k_xmax<<<dim3(512), dim3(256), 0, stream>>>((const float4*)x, wsu);
  k_wq<<<dim3(1), dim3(1024), 0, stream>>>(wih, whh, w1, w2, w3, wsu);

  void* args[] = {(void*)&x,  (void*)&bih, (void*)&bhh, (void*)&b1,
                  (void*)&b2, (void*)&b3,  (void*)&out, (void*)&wsu};
  hipLaunchCooperativeKernel(k_lstm, dim3(NB), dim3(NT), args, 0, stream);
}

// Round 4
// 2043.414 us; speedup vs baseline: 2.7481x; 1.3407x over previous
//
#include <hip/hip_runtime.h>

// ---------------- problem constants ----------------
constexpr int Tn  = 256;     // timesteps
constexpr int INn = 10;      // input features
constexpr int Hn  = 20;      // hidden
constexpr int G4  = 80;      // 4*H
constexpr int Bn  = 8192;    // batch

constexpr int NB  = 256;     // cooperative grid blocks (1 per CU)
constexpr int NT  = 256;     // threads per block
constexpr int NW  = NT / 64; // waves per block = 4
constexpr int BPB = Bn / NB; // batch rows per block = 32
constexpr int PREP = 81;     // padded s_pre leading dim

// ---------------- ws layout ----------------
// ring (u64): [2][NB] epoch-tagged partial slots; relaxed agent atomics only.
constexpr int RING_U64  = 2 * NB;                // 512 u64 = 4 KB

constexpr int WS_XMAX   = 1040;                  // u32 idx (past ring)
constexpr int WS_SX     = 1041;                  // f32 x-scale
constexpr int WS_WIH    = 1088;                  // 800  quantized w_ih
constexpr int WS_WHH    = WS_WIH + G4 * INn;     // 1600 quantized w_hh
constexpr int WS_W1     = WS_WHH + G4 * Hn;      // 1280
constexpr int WS_W2     = WS_W1 + 64 * Hn;       // 2048
constexpr int WS_W3     = WS_W2 + 32 * 64;       // 160
constexpr int WS_END    = WS_W3 + 5 * 32;        // ~26 KB total

constexpr float SIGS = (float)(1.0 / 63.0);
constexpr float TANS = (float)(1.0 / 31.0);
// exact double reciprocals of the f32 scale constants (compile-time)
constexpr double RS_SIG = 1.0 / (double)SIGS;
constexpr double RS_TAN = 1.0 / (double)TANS;

__device__ __forceinline__ float wave_bmax64(float v) {
#pragma unroll
  for (int off = 32; off; off >>= 1) v = fmaxf(v, __shfl_xor(v, off, 64));
  return v;  // result in ALL lanes
}

// v/s as correctly-rounded f32 via f64 multiply by precomputed 1/s.
__device__ __forceinline__ float divrs(float v, double rs) {
  return (float)((double)v * rs);
}
// quant with runtime scale, exact f32 divide (s2/s3 paths)
__device__ __forceinline__ float quantq(float v, float s, float lo, float hi) {
  return __fmul_rn(rintf(fminf(fmaxf(v / s, lo), hi)), s);
}
// quant with precomputed double reciprocal
__device__ __forceinline__ float quantr(float v, double rs, float s, float lo,
                                        float hi) {
  return __fmul_rn(rintf(fminf(fmaxf(divrs(v, rs), lo), hi)), s);
}
__device__ __forceinline__ float sigm(float v) {
  return 1.0f / (1.0f + expf(-v));
}

__device__ __forceinline__ unsigned long long ring_ld(unsigned long long* p) {
  return __hip_atomic_load(p, __ATOMIC_RELAXED, __HIP_MEMORY_SCOPE_AGENT);
}
__device__ __forceinline__ void ring_st(unsigned long long* p,
                                        unsigned long long v) {
  __hip_atomic_store(p, v, __ATOMIC_RELAXED, __HIP_MEMORY_SCOPE_AGENT);
}

// ---- grid-wide max, flat one-hop, split begin/end so callers can overlap ----
// begin: block-reduce + one epoch-tagged partial store per block.
// end:   wave 0 polls all NB slots (4 u64/lane), butterfly-reduce, LDS bcast.
// 2-deep ring is WAR-safe: any store at inst k+2 requires every block to have
// completed its poll at inst k (proof: store@k+2 needs detect@k+1 which needs
// all partials@k+1, each stored only after that block's detect@k).
__device__ __forceinline__ void gm_begin(float v, int inst,
                                         unsigned long long* ring,
                                         float* s_red) {
  const int tid = threadIdx.x;
  v = wave_bmax64(v);
  if ((tid & 63) == 0) s_red[tid >> 6] = v;
  __syncthreads();  // also orders this phase's LDS writes before next reads
  if (tid == 0) {
    float bm = fmaxf(fmaxf(s_red[0], s_red[1]), fmaxf(s_red[2], s_red[3]));
    ring_st(&ring[(inst & 1) * NB + blockIdx.x],
            ((unsigned long long)(unsigned)inst << 32) | __float_as_uint(bm));
  }
}

__device__ __forceinline__ float gm_end(int inst, unsigned long long* ring,
                                        float* s_bc) {
  const int tid = threadIdx.x;
  const unsigned long long tag = (unsigned long long)(unsigned)inst << 32;
  const int base = (inst & 1) * NB;
  if (tid < 64) {
    const int i0 = base + tid * 4;
    unsigned long long w0, w1, w2, w3;
    do {
      w0 = ring_ld(&ring[i0 + 0]);
      w1 = ring_ld(&ring[i0 + 1]);
      w2 = ring_ld(&ring[i0 + 2]);
      w3 = ring_ld(&ring[i0 + 3]);
    } while ((((w0 ^ tag) | (w1 ^ tag) | (w2 ^ tag) | (w3 ^ tag)) >> 32) != 0ull);
    float m = fmaxf(
        fmaxf(__uint_as_float((unsigned)w0), __uint_as_float((unsigned)w1)),
        fmaxf(__uint_as_float((unsigned)w2), __uint_as_float((unsigned)w3)));
    m = wave_bmax64(m);
    if (tid == 0) *s_bc = m;
  }
  __syncthreads();
  return *s_bc;
}

// ---------------- setup kernels ----------------
__global__ void k_init(unsigned long long* ring, unsigned* wsu) {
  int i = threadIdx.x;  // 1024 threads
  if (i < RING_U64) ring[i] = 0xFFFFFFFF00000000ull;
  if (i == 0) wsu[WS_XMAX] = 0u;
}

__global__ void k_xmax(const float4* __restrict__ x4, unsigned* wsu) {
  float m = 0.f;
  int idx = blockIdx.x * blockDim.x + threadIdx.x;
  int stride = gridDim.x * blockDim.x;
  for (int i = idx; i < (Bn * Tn * INn) / 4; i += stride) {
    float4 v = x4[i];
    m = fmaxf(m, fmaxf(fmaxf(fabsf(v.x), fabsf(v.y)),
                       fmaxf(fabsf(v.z), fabsf(v.w))));
  }
  m = wave_bmax64(m);
  __shared__ float sred[4];
  if ((threadIdx.x & 63) == 0) sred[threadIdx.x >> 6] = m;
  __syncthreads();
  if (threadIdx.x == 0) {
    m = fmaxf(fmaxf(sred[0], sred[1]), fmaxf(sred[2], sred[3]));
    atomicMax(&wsu[WS_XMAX], __float_as_uint(m));  // non-neg f32: bit-monotone
  }
}

__device__ void quant_tensor(const float* __restrict__ src, int n, float* dst,
                             float* sred, float* sb, int nt) {
  const int tid = threadIdx.x;
  float m = 0.f;
  for (int i = tid; i < n; i += nt) m = fmaxf(m, fabsf(src[i]));
  m = wave_bmax64(m);
  __syncthreads();
  if ((tid & 63) == 0) sred[tid >> 6] = m;
  __syncthreads();
  if (tid == 0) {
    float bm = sred[0];
    for (int w = 1; w < nt / 64; ++w) bm = fmaxf(bm, sred[w]);
    *sb = __fadd_rn(bm / 127.0f, 1e-8f);
  }
  __syncthreads();
  float s = *sb;
  for (int i = tid; i < n; i += nt) {
    float q = rintf(fminf(fmaxf(src[i] / s, -128.f), 127.f));
    dst[i] = __fmul_rn(q, s);
  }
}

__global__ __launch_bounds__(1024) void k_wq(const float* wih, const float* whh,
                                             const float* w1, const float* w2,
                                             const float* w3, unsigned* wsu) {
  float* wsf = (float*)wsu;
  __shared__ float sred[16];
  __shared__ float sb;
  if (threadIdx.x == 0)
    wsf[WS_SX] = __fadd_rn(__uint_as_float(wsu[WS_XMAX]) / 127.0f, 1e-8f);
  quant_tensor(wih, G4 * INn, wsf + WS_WIH, sred, &sb, 1024);
  quant_tensor(whh, G4 * Hn,  wsf + WS_WHH, sred, &sb, 1024);
  quant_tensor(w1,  64 * Hn,  wsf + WS_W1,  sred, &sb, 1024);
  quant_tensor(w2,  32 * 64,  wsf + WS_W2,  sred, &sb, 1024);
  quant_tensor(w3,  5 * 32,   wsf + WS_W3,  sred, &sb, 1024);
}

// ---------------- main cooperative LSTM kernel ----------------
__global__ __launch_bounds__(NT, 1) void k_lstm(
    const float* __restrict__ x,
    const float* __restrict__ bih, const float* __restrict__ bhh,
    const float* __restrict__ b1, const float* __restrict__ b2,
    const float* __restrict__ b3,
    float* __restrict__ out, unsigned* __restrict__ wsu) {
  const float* wsf = (const float*)wsu;
  unsigned long long* ring = (unsigned long long*)wsu;

  __shared__ float s_wih[G4][INn];
  __shared__ float s_whh[G4][Hn];
  __shared__ float s_bih[G4], s_bhh[G4];
  __shared__ float s_h[BPB][Hn];       // persistent hidden state
  __shared__ float s_c[BPB][Hn];       // persistent cell state
  __shared__ float s_pre[BPB][PREP];   // pre-gates (padded); reused as l1
  __shared__ float s_xs[BPB][INn];     // quantized x slice
  __shared__ float s_l2[BPB][32];
  __shared__ float s_red[NW];
  __shared__ float s_bc;

  const int tid = threadIdx.x;
  const int b0 = blockIdx.x * BPB;

  for (int i = tid; i < G4 * INn; i += NT) (&s_wih[0][0])[i] = wsf[WS_WIH + i];
  for (int i = tid; i < G4 * Hn; i += NT) (&s_whh[0][0])[i] = wsf[WS_WHH + i];
  if (tid < G4) { s_bih[tid] = bih[tid]; s_bhh[tid] = bhh[tid]; }
  for (int i = tid; i < BPB * Hn; i += NT) {
    (&s_h[0][0])[i] = 0.f;
    (&s_c[0][0])[i] = 0.f;
  }
  const float sx = wsf[WS_SX];
  const double rsx = 1.0 / (double)sx;

  const int bl = tid >> 3;        // batch row (0..31) for matmul
  const int g0 = (tid & 7) * 10;  // first of 10 gate columns

  // x staging mapping: e0 = tid (always < 320), e1 = 256+tid (tid<64)
  const int bi0 = tid / INn, ii0 = tid - bi0 * INn;
  const int e1 = NT + tid;
  const int bi1 = e1 / INn, ii1 = e1 - bi1 * INn;
  const bool has1 = (e1 < BPB * INn);

  // stage + quantize x(t=0)
  {
    float v = x[((b0 + bi0) * Tn + 0) * INn + ii0];
    s_xs[bi0][ii0] = __fmul_rn(rintf(fminf(fmaxf(divrs(v, rsx), -128.f), 127.f)), sx);
    if (has1) {
      float v1 = x[((b0 + bi1) * Tn + 0) * INn + ii1];
      s_xs[bi1][ii1] = __fmul_rn(rintf(fminf(fmaxf(divrs(v1, rsx), -128.f), 127.f)), sx);
    }
  }
  __syncthreads();

  // xacc(t=0): x-contribution + both biases for this thread's 10 gates
  float xacc[10];
  {
    float xr[INn];
#pragma unroll
    for (int i = 0; i < INn; i++) xr[i] = s_xs[bl][i];
#pragma unroll
    for (int gg = 0; gg < 10; ++gg) {
      int g = g0 + gg;
      float acc = 0.f;
#pragma unroll
      for (int i = 0; i < INn; i++) acc = fmaf(xr[i], s_wih[g][i], acc);
      acc = __fadd_rn(acc, s_bih[g]);
      xacc[gg] = __fadd_rn(acc, s_bhh[g]);
    }
  }

  int inst = 0;

  for (int t = 0; t < Tn; ++t) {
    const bool more = (t + 1 < Tn);

    // ---- phase A: pre-gates = xacc + h@whh^T ----
    float hreg[Hn];
#pragma unroll
    for (int k = 0; k < Hn; k++) hreg[k] = s_h[bl][k];
    float lm = 0.f;
#pragma unroll
    for (int gg = 0; gg < 10; ++gg) {
      int g = g0 + gg;
      float hd = 0.f;
#pragma unroll
      for (int k = 0; k < Hn; k++) hd = fmaf(hreg[k], s_whh[g][k], hd);
      float pre = __fadd_rn(xacc[gg], hd);
      s_pre[bl][g] = pre;
      lm = fmaxf(lm, fabsf(pre));
    }
    gm_begin(lm, inst, ring, s_red);
    // s1 window: issue x(t+1) global loads
    float xr0 = 0.f, xr1 = 0.f;
    if (more) {
      xr0 = x[((b0 + bi0) * Tn + (t + 1)) * INn + ii0];
      if (has1) xr1 = x[((b0 + bi1) * Tn + (t + 1)) * INn + ii1];
    }
    float s1v = __fadd_rn(gm_end(inst, ring, &s_bc) / 31.0f, 1e-8f);
    inst++;
    const double rs1 = 1.0 / (double)s1v;

    // ---- phase B: gate quant + nonlinearities + cell pre-activation ----
    float cpre[3], og[3], hpre[3];
    float lm2 = 0.f;
#pragma unroll
    for (int k = 0; k < 3; k++) {
      int e = tid + k * NT;
      if (e < BPB * Hn) {
        int cb = e / Hn, j = e - cb * Hn;
        float gi = quantr(s_pre[cb][j],      rs1, s1v, -32.f, 31.f);
        float gf = quantr(s_pre[cb][20 + j], rs1, s1v, -32.f, 31.f);
        float gg = quantr(s_pre[cb][40 + j], rs1, s1v, -32.f, 31.f);
        float go = quantr(s_pre[cb][60 + j], rs1, s1v, -32.f, 31.f);
        float iv = quantr(sigm(gi), RS_SIG, SIGS, 0.f, 63.f);
        float fv = quantr(sigm(gf), RS_SIG, SIGS, 0.f, 63.f);
        float gv = quantr(tanhf(gg), RS_TAN, TANS, -32.f, 31.f);
        og[k]    = quantr(sigm(go), RS_SIG, SIGS, 0.f, 63.f);
        float cp = __fadd_rn(__fmul_rn(fv, s_c[cb][j]), __fmul_rn(iv, gv));
        cpre[k] = cp;
        lm2 = fmaxf(lm2, fabsf(cp));
      }
    }
    gm_begin(lm2, inst, ring, s_red);
    // s2 window: write quantized x(t+1) to LDS (x(t) reads all done pre-s1)
    if (more) {
      s_xs[bi0][ii0] = __fmul_rn(rintf(fminf(fmaxf(divrs(xr0, rsx), -128.f), 127.f)), sx);
      if (has1)
        s_xs[bi1][ii1] = __fmul_rn(rintf(fminf(fmaxf(divrs(xr1, rsx), -128.f), 127.f)), sx);
    }
    float s2v = __fadd_rn(gm_end(inst, ring, &s_bc) / 31.0f, 1e-8f);
    inst++;

    // ---- phase C: cell quant, tanh, h pre-activation ----
    float lm3 = 0.f;
#pragma unroll
    for (int k = 0; k < 3; k++) {
      int e = tid + k * NT;
      if (e < BPB * Hn) {
        int cb = e / Hn, j = e - cb * Hn;
        float cn = quantq(cpre[k], s2v, -32.f, 31.f);
        s_c[cb][j] = cn;
        float tq = quantr(tanhf(cn), RS_TAN, TANS, -32.f, 31.f);
        float hp = __fmul_rn(og[k], tq);
        hpre[k] = hp;
        lm3 = fmaxf(lm3, fabsf(hp));
      }
    }
    gm_begin(lm3, inst, ring, s_red);
    // s3 window: compute xacc(t+1) from s_xs (ordered by gm_begin's barrier)
    if (more) {
      float xr[INn];
#pragma unroll
      for (int i = 0; i < INn; i++) xr[i] = s_xs[bl][i];
#pragma unroll
      for (int gg = 0; gg < 10; ++gg) {
        int g = g0 + gg;
        float acc = 0.f;
#pragma unroll
        for (int i = 0; i < INn; i++) acc = fmaf(xr[i], s_wih[g][i], acc);
        acc = __fadd_rn(acc, s_bih[g]);
        xacc[gg] = __fadd_rn(acc, s_bhh[g]);
      }
    }
    float s3v = __fadd_rn(gm_end(inst, ring, &s_bc) / 127.0f, 1e-8f);
    inst++;

#pragma unroll
    for (int k = 0; k < 3; k++) {
      int e = tid + k * NT;
      if (e < BPB * Hn) {
        int cb = e / Hn, j = e - cb * Hn;
        s_h[cb][j] = quantq(hpre[k], s3v, -128.f, 127.f);
      }
    }
    __syncthreads();  // order s_h writes before next phase-A reads
  }

  // ---------------- MLP head ----------------
  // out0 = qrelu(hT, 6), in place in s_h
  {
    float r[3];
    float lm = 0.f;
#pragma unroll
    for (int k = 0; k < 3; k++) {
      int e = tid + k * NT;
      if (e < BPB * Hn) {
        r[k] = fmaxf((&s_h[0][0])[e], 0.f);
        lm = fmaxf(lm, r[k]);
      }
    }
    gm_begin(lm, inst, ring, s_red);
    float s = __fadd_rn(gm_end(inst, ring, &s_bc) / 63.0f, 1e-8f);
    inst++;
#pragma unroll
    for (int k = 0; k < 3; k++) {
      int e = tid + k * NT;
      if (e < BPB * Hn)
        (&s_h[0][0])[e] = __fmul_rn(rintf(fminf(fmaxf(r[k] / s, 0.f), 63.f)), s);
    }
  }
  __syncthreads();

  // l1 = qrelu(out0 @ w1^T + b1, 6) -> s_l1 (aliases s_pre, 2048 <= 32*81)
  float* s_l1 = &s_pre[0][0];
  {
    float a[8];
    float lm = 0.f;
#pragma unroll
    for (int k = 0; k < 8; k++) {
      int o = tid + k * NT;
      int cb = o >> 6, j = o & 63;
      float acc = 0.f;
#pragma unroll
      for (int kk = 0; kk < Hn; kk++)
        acc = fmaf(s_h[cb][kk], wsf[WS_W1 + j * Hn + kk], acc);
      acc = __fadd_rn(acc, b1[j]);
      acc = fmaxf(acc, 0.f);
      a[k] = acc;
      lm = fmaxf(lm, acc);
    }
    gm_begin(lm, inst, ring, s_red);
    float s = __fadd_rn(gm_end(inst, ring, &s_bc) / 63.0f, 1e-8f);
    inst++;
#pragma unroll
    for (int k = 0; k < 8; k++) {
      int o = tid + k * NT;
      s_l1[o] = __fmul_rn(rintf(fminf(fmaxf(a[k] / s, 0.f), 63.f)), s);
    }
  }
  __syncthreads();

  // l2 = qrelu(l1 @ w2^T + b2, 6) -> s_l2
  {
    float a[4];
    float lm = 0.f;
#pragma unroll
    for (int k = 0; k < 4; k++) {
      int o = tid + k * NT;
      int cb = o >> 5, j = o & 31;
      float acc = 0.f;
#pragma unroll
      for (int kk = 0; kk < 64; kk++)
        acc = fmaf(s_l1[cb * 64 + kk], wsf[WS_W2 + j * 64 + kk], acc);
      acc = __fadd_rn(acc, b2[j]);
      acc = fmaxf(acc, 0.f);
      a[k] = acc;
      lm = fmaxf(lm, acc);
    }
    gm_begin(lm, inst, ring, s_red);
    float s = __fadd_rn(gm_end(inst, ring, &s_bc) / 63.0f, 1e-8f);
    inst++;
#pragma unroll
    for (int k = 0; k < 4; k++) {
      int o = tid + k * NT;
      int cb = o >> 5, j = o & 31;
      s_l2[cb][j] = __fmul_rn(rintf(fminf(fmaxf(a[k] / s, 0.f), 63.f)), s);
    }
  }
  __syncthreads();

  // out = l2 @ w3^T + b3
  if (tid < BPB * 5) {
    int cb = tid / 5, j = tid - cb * 5;
    float acc = 0.f;
#pragma unroll
    for (int kk = 0; kk < 32; kk++)
      acc = fmaf(s_l2[cb][kk], wsf[WS_W3 + j * 32 + kk], acc);
    acc = __fadd_rn(acc, b3[j]);
    out[(b0 + cb) * 5 + j] = acc;
  }
}

extern "C" void kernel_launch(void* const* d_in, const int* in_sizes, int n_in,
                              void* d_out, int out_size, void* d_ws,
                              size_t ws_size, hipStream_t stream) {
  const float* x   = (const float*)d_in[0];
  const float* wih = (const float*)d_in[1];
  const float* whh = (const float*)d_in[2];
  const float* bih = (const float*)d_in[3];
  const float* bhh = (const float*)d_in[4];
  const float* w1  = (const float*)d_in[5];
  const float* b1  = (const float*)d_in[6];
  const float* w2  = (const float*)d_in[7];
  const float* b2  = (const float*)d_in[8];
  const float* w3  = (const float*)d_in[9];
  const float* b3  = (const float*)d_in[10];
  float* out = (float*)d_out;
  unsigned* wsu = (unsigned*)d_ws;
  unsigned long long* ring = (unsigned long long*)d_ws;

  k_init<<<dim3(1), dim3(1024), 0, stream>>>(ring, wsu);
  k_xmax<<<dim3(512), dim3(256), 0, stream>>>((const float4*)x, wsu);
  k_wq<<<dim3(1), dim3(1024), 0, stream>>>(wih, whh, w1, w2, w3, wsu);

  void* args[] = {(void*)&x,  (void*)&bih, (void*)&bhh, (void*)&b1,
                  (void*)&b2, (void*)&b3,  (void*)&out, (void*)&wsu};
  hipLaunchCooperativeKernel(k_lstm, dim3(NB), dim3(NT), args, 0, stream);
}